// Round 2
// baseline (89.138 us; speedup 1.0000x reference)
//
#include <hip/hip_runtime.h>
#include <hip/hip_bf16.h>

#define ALPHA 0.2f
#define LOG2E 1.4426950408889634f

typedef __attribute__((ext_vector_type(8))) short bf16x8;
typedef __attribute__((ext_vector_type(8))) unsigned short u16x8;
typedef __attribute__((ext_vector_type(4))) float f32x4;
typedef __attribute__((ext_vector_type(4))) int i32x4;

__device__ __forceinline__ unsigned short f2bf(float x) {
    // round-to-nearest-even fp32 -> bf16 (finite inputs only)
    unsigned int u = __float_as_uint(x);
    unsigned int r = (u + 0x7FFFu + ((u >> 16) & 1u)) >> 16;
    return (unsigned short)r;
}

__device__ __forceinline__ int cvt_pk_bf16(float lo, float hi) {
    int r;
    asm("v_cvt_pk_bf16_f32 %0, %1, %2" : "=v"(r) : "v"(lo), "v"(hi));
    return r;
}

// ---------------------------------------------------------------------------
// Kernel A: Wh = h @ W (fp32), si2 = (Wh@a1)*log2e, sj2 = (Wh@a2)*log2e,
// WhT = bf16(Wh)^T.  Block: 256 threads / 64 rows; grid 256.
// ---------------------------------------------------------------------------
__global__ __launch_bounds__(256) void gat_precompute(
    const float* __restrict__ h, const float* __restrict__ W,
    const float* __restrict__ a, unsigned short* __restrict__ WhT,
    float* __restrict__ si2, float* __restrict__ sj2)
{
    __shared__ float h_lds[64][128];
    __shared__ float wh_lds[64][65];   // +1 pad: conflict-free transpose reads
    const int tid  = threadIdx.x;
    const int lane = tid & 63;
    const int wave = tid >> 6;
    const long long row0 = (long long)blockIdx.x * 64;

    {
        const float4* s4 = (const float4*)(h + row0 * 128);
        #pragma unroll
        for (int i = 0; i < 8; ++i) {
            int idx = tid + i * 256;
            float4 v = s4[idx];
            int r = idx >> 5;
            int f = (idx & 31) * 4;
            *(float4*)&h_lds[r][f] = v;
        }
    }
    __syncthreads();

    const float a1 = a[lane];
    const float a2 = a[64 + lane];
    float acc[16];
    #pragma unroll
    for (int r = 0; r < 16; ++r) acc[r] = 0.0f;

    for (int f = 0; f < 128; f += 4) {
        const float w0 = W[(f+0)*64 + lane];
        const float w1 = W[(f+1)*64 + lane];
        const float w2 = W[(f+2)*64 + lane];
        const float w3 = W[(f+3)*64 + lane];
        #pragma unroll
        for (int r = 0; r < 16; ++r) {
            const float4 hv = *(const float4*)&h_lds[wave*16 + r][f];
            acc[r] = fmaf(hv.x, w0, acc[r]);
            acc[r] = fmaf(hv.y, w1, acc[r]);
            acc[r] = fmaf(hv.z, w2, acc[r]);
            acc[r] = fmaf(hv.w, w3, acc[r]);
        }
    }

    #pragma unroll
    for (int r = 0; r < 16; ++r) {
        const int rr = wave*16 + r;
        wh_lds[rr][lane] = acc[r];
        float s1 = acc[r] * a1;
        float s2 = acc[r] * a2;
        #pragma unroll
        for (int off = 32; off > 0; off >>= 1) {
            s1 += __shfl_xor(s1, off);
            s2 += __shfl_xor(s2, off);
        }
        if (lane == 0) {
            si2[row0 + rr] = s1 * LOG2E;
            sj2[row0 + rr] = s2 * LOG2E;
        }
    }
    __syncthreads();

    const long long b  = row0 >> 11;
    const int n0 = (int)(row0 & 2047);
    const int o  = tid >> 2;
    const int c0 = (tid & 3) * 16;
    unsigned short* dst = WhT + (b*64 + o)*2048 + n0 + c0;
    u16x8 v0, v1;
    #pragma unroll
    for (int k = 0; k < 8; ++k) v0[k] = f2bf(wh_lds[c0 + k][o]);
    #pragma unroll
    for (int k = 0; k < 8; ++k) v1[k] = f2bf(wh_lds[c0 + 8 + k][o]);
    *(u16x8*)dst       = v0;
    *(u16x8*)(dst + 8) = v1;
}

// ---------------------------------------------------------------------------
// Kernel A2: sjmax[b] = max_j sj2[b][j].  Grid 8 x 256 threads.
// ---------------------------------------------------------------------------
__global__ __launch_bounds__(256) void gat_sjmax(
    const float* __restrict__ sj2, float* __restrict__ sjmax)
{
    __shared__ float red[4];
    const int b   = blockIdx.x;
    const int tid = threadIdx.x;
    const float4* s4 = (const float4*)(sj2 + b * 2048);
    const float4 v0 = s4[tid];
    const float4 v1 = s4[tid + 256];
    float m = fmaxf(fmaxf(fmaxf(v0.x, v0.y), fmaxf(v0.z, v0.w)),
                    fmaxf(fmaxf(v1.x, v1.y), fmaxf(v1.z, v1.w)));
    #pragma unroll
    for (int off = 32; off > 0; off >>= 1) m = fmaxf(m, __shfl_xor(m, off));
    if ((tid & 63) == 0) red[tid >> 6] = m;
    __syncthreads();
    if (tid == 0)
        sjmax[b] = fmaxf(fmaxf(red[0], red[1]), fmaxf(red[2], red[3]));
}

// ---------------------------------------------------------------------------
// Kernel B: fused masked-softmax attention with a FIXED per-row max
// (m = lrelu(si + sjmax) >= every unmasked score, lrelu monotone).
// Block = (batch, 16-row tile); 4 waves x 512-j quarters. Per 32-j chunk:
// nontemporal adj loads (prefetched 1 deep) -> p = exp2(lrelu-m)*mask ->
// bf16 P (v_cvt_pk) -> 4x mfma vs WhT frags + 1x mfma vs ones (row sums).
// No online rescaling, no per-chunk cross-lane ops.
// ---------------------------------------------------------------------------
__global__ __launch_bounds__(256, 4) void gat_attention(
    const int* __restrict__ adj, const unsigned short* __restrict__ WhT,
    const float* __restrict__ si2, const float* __restrict__ sj2,
    const float* __restrict__ sjmax, float* __restrict__ out)
{
    __shared__ float l_lds[4][16];
    __shared__ float acc_lds[4][16][64];

    const int tid  = threadIdx.x;
    const int lane = tid & 63;
    const int wave = tid >> 6;
    const int bid  = blockIdx.x;
    const int b    = bid >> 7;
    const int i0   = (bid & 127) << 4;

    const int arow = lane & 15;          // A-row / B-col index within tile
    const int g    = lane >> 4;          // k-group

    const float* sjb  = sj2 + b * 2048;
    const float  mysi = si2[b * 2048 + i0 + arow];
    const float  u    = mysi + sjmax[b];
    const float  m2   = fmaxf(u, ALPHA * u);   // fixed row max (log2 domain)
    const unsigned short* whb = WhT + (long long)b * 64 * 2048;
    const int* aptr = adj + (((long long)b * 2048) + i0 + arow) * 2048
                          + wave * 512 + g * 8;

    f32x4 accf[4];
    #pragma unroll
    for (int ob = 0; ob < 4; ++ob) accf[ob] = (f32x4){0.f, 0.f, 0.f, 0.f};
    f32x4 accl = (f32x4){0.f, 0.f, 0.f, 0.f};

    bf16x8 ones;
    #pragma unroll
    for (int k = 0; k < 8; ++k) ones[k] = (short)0x3F80;   // bf16 1.0

    const int jbase = wave * 512 + g * 8;

    auto process = [&](i32x4 A0, i32x4 A1, int jl) {
        const f32x4 S0 = *(const f32x4*)(sjb + jl);
        const f32x4 S1 = *(const f32x4*)(sjb + jl + 4);
        float p[8];
        #pragma unroll
        for (int k = 0; k < 8; ++k) {
            const float t  = mysi + (k < 4 ? S0[k] : S1[k - 4]);
            const float x  = fmaxf(t, ALPHA * t);            // lrelu (log2 dom)
            const float pe = __builtin_amdgcn_exp2f(x - m2); // <= 1
            const int   av = (k < 4 ? A0[k] : A1[k - 4]);
            p[k] = av > 0 ? pe : 0.0f;
        }
        i32x4 pk;
        pk[0] = cvt_pk_bf16(p[0], p[1]);
        pk[1] = cvt_pk_bf16(p[2], p[3]);
        pk[2] = cvt_pk_bf16(p[4], p[5]);
        pk[3] = cvt_pk_bf16(p[6], p[7]);
        const bf16x8 pa = __builtin_bit_cast(bf16x8, pk);

        accl = __builtin_amdgcn_mfma_f32_16x16x32_bf16(pa, ones, accl, 0, 0, 0);
        #pragma unroll
        for (int ob = 0; ob < 4; ++ob) {
            const bf16x8 bfr =
                *(const bf16x8*)(whb + (long long)(ob*16 + arow)*2048 + jl);
            accf[ob] = __builtin_amdgcn_mfma_f32_16x16x32_bf16(pa, bfr, accf[ob], 0, 0, 0);
        }
    };

    i32x4 A0 = __builtin_nontemporal_load((const i32x4*)aptr);
    i32x4 A1 = __builtin_nontemporal_load((const i32x4*)(aptr + 4));
    #pragma unroll 2
    for (int jc = 0; jc < 480; jc += 32) {
        const i32x4 N0 = __builtin_nontemporal_load((const i32x4*)(aptr + jc + 32));
        const i32x4 N1 = __builtin_nontemporal_load((const i32x4*)(aptr + jc + 36));
        process(A0, A1, jbase + jc);
        A0 = N0; A1 = N1;
    }
    process(A0, A1, jbase + 480);

    // ---- combine the 4 j-quarter partials (shared m => plain sums) ----
    if (arow == 0) {
        #pragma unroll
        for (int r = 0; r < 4; ++r) l_lds[wave][g*4 + r] = accl[r];
    }
    #pragma unroll
    for (int r = 0; r < 4; ++r) {
        #pragma unroll
        for (int ob = 0; ob < 4; ++ob)
            acc_lds[wave][g*4 + r][ob*16 + arow] = accf[ob][r];
    }
    __syncthreads();

    const int oo = tid & 63;
    for (int rr = tid >> 6; rr < 16; rr += 4) {
        const float L = l_lds[0][rr] + l_lds[1][rr] + l_lds[2][rr] + l_lds[3][rr];
        const float s = acc_lds[0][rr][oo] + acc_lds[1][rr][oo]
                      + acc_lds[2][rr][oo] + acc_lds[3][rr][oo];
        out[(((long long)b*2048) + i0 + rr)*64 + oo] = s / L;
    }
}

// ---------------------------------------------------------------------------
extern "C" void kernel_launch(void* const* d_in, const int* in_sizes, int n_in,
                              void* d_out, int out_size, void* d_ws, size_t ws_size,
                              hipStream_t stream) {
    const float* h   = (const float*)d_in[0];
    const int*   adj = (const int*)d_in[1];
    const float* W   = (const float*)d_in[2];
    const float* a   = (const float*)d_in[3];
    float* out = (float*)d_out;

    unsigned short* WhT = (unsigned short*)d_ws;                    // 2 MB
    float* si2   = (float*)((char*)d_ws + (size_t)8*64*2048*2);
    float* sj2   = si2 + 8*2048;
    float* sjmax = sj2 + 8*2048;

    gat_precompute<<<256, 256, 0, stream>>>(h, W, a, WhT, si2, sj2);
    gat_sjmax<<<8, 256, 0, stream>>>(sj2, sjmax);
    gat_attention<<<1024, 256, 0, stream>>>(adj, WhT, si2, sj2, sjmax, out);
}

// Round 3
// 66.575 us; speedup vs baseline: 1.3389x; 1.3389x over previous
//
#include <hip/hip_runtime.h>
#include <hip/hip_bf16.h>

#define ALPHA 0.2f
#define LOG2E 1.4426950408889634f

typedef __attribute__((ext_vector_type(8))) short bf16x8;
typedef __attribute__((ext_vector_type(8))) unsigned short u16x8;
typedef __attribute__((ext_vector_type(4))) float f32x4;
typedef __attribute__((ext_vector_type(4))) int i32x4;

__device__ __forceinline__ int cvt_pk_bf16(float lo, float hi) {
    int r;
    asm("v_cvt_pk_bf16_f32 %0, %1, %2" : "=v"(r) : "v"(lo), "v"(hi));
    return r;
}

// ---------------------------------------------------------------------------
// Kernel A: Wh = h @ W (fp32), si2 = (Wh@a1)*log2e, sj2 = (Wh@a2)*log2e,
// WhT = bf16(Wh)^T.  512 blocks x 256 threads, 32 rows/block (2 blocks/CU).
// ---------------------------------------------------------------------------
__global__ __launch_bounds__(256) void gat_precompute(
    const float* __restrict__ h, const float* __restrict__ W,
    const float* __restrict__ a, unsigned short* __restrict__ WhT,
    float* __restrict__ si2, float* __restrict__ sj2)
{
    __shared__ float h_lds[32][128];
    __shared__ float wh_lds[32][65];   // +1 pad
    const int tid  = threadIdx.x;
    const int lane = tid & 63;
    const int wave = tid >> 6;
    const long long row0 = (long long)blockIdx.x * 32;

    {
        const float4* s4 = (const float4*)(h + row0 * 128);
        #pragma unroll
        for (int i = 0; i < 4; ++i) {
            int idx = tid + i * 256;          // 0..1023 float4s
            float4 v = s4[idx];
            int r = idx >> 5;
            int f = (idx & 31) * 4;
            *(float4*)&h_lds[r][f] = v;
        }
    }
    __syncthreads();

    const float a1 = a[lane];
    const float a2 = a[64 + lane];
    float acc[8];
    #pragma unroll
    for (int r = 0; r < 8; ++r) acc[r] = 0.0f;

    for (int f = 0; f < 128; f += 4) {
        const float w0 = W[(f+0)*64 + lane];
        const float w1 = W[(f+1)*64 + lane];
        const float w2 = W[(f+2)*64 + lane];
        const float w3 = W[(f+3)*64 + lane];
        #pragma unroll
        for (int r = 0; r < 8; ++r) {
            const float4 hv = *(const float4*)&h_lds[wave*8 + r][f];
            acc[r] = fmaf(hv.x, w0, acc[r]);
            acc[r] = fmaf(hv.y, w1, acc[r]);
            acc[r] = fmaf(hv.z, w2, acc[r]);
            acc[r] = fmaf(hv.w, w3, acc[r]);
        }
    }

    #pragma unroll
    for (int r = 0; r < 8; ++r) {
        const int rr = wave*8 + r;
        wh_lds[rr][lane] = acc[r];
        float s1 = acc[r] * a1;
        float s2 = acc[r] * a2;
        #pragma unroll
        for (int off = 32; off > 0; off >>= 1) {
            s1 += __shfl_xor(s1, off);
            s2 += __shfl_xor(s2, off);
        }
        if (lane == 0) {
            si2[row0 + rr] = s1 * LOG2E;
            sj2[row0 + rr] = s2 * LOG2E;
        }
    }
    __syncthreads();

    // transposed bf16 write: 64 o-rows x 32 n-cols
    const long long b  = row0 >> 11;
    const int n0 = (int)(row0 & 2047);
    const int o  = tid >> 2;
    const int c0 = (tid & 3) * 8;
    i32x4 pk;
    #pragma unroll
    for (int k = 0; k < 4; ++k)
        pk[k] = cvt_pk_bf16(wh_lds[c0 + 2*k][o], wh_lds[c0 + 2*k + 1][o]);
    *(i32x4*)(WhT + (b*64 + o)*2048 + n0 + c0) = pk;
}

// ---------------------------------------------------------------------------
// Kernel S: per-batch sjmax + factorized-exp tables FH[j] = (2^sj, 2^(0.2 sj)).
// Grid 8 x 256.
// ---------------------------------------------------------------------------
__global__ __launch_bounds__(256) void gat_tables(
    const float* __restrict__ sj2, float* __restrict__ sjmax,
    float* __restrict__ FH)
{
    __shared__ float red[4];
    const int b   = blockIdx.x;
    const int tid = threadIdx.x;
    const float4* s4 = (const float4*)(sj2 + b * 2048);
    const float4 v0 = s4[tid];
    const float4 v1 = s4[tid + 256];
    float m = fmaxf(fmaxf(fmaxf(v0.x, v0.y), fmaxf(v0.z, v0.w)),
                    fmaxf(fmaxf(v1.x, v1.y), fmaxf(v1.z, v1.w)));
    #pragma unroll
    for (int off = 32; off > 0; off >>= 1) m = fmaxf(m, __shfl_xor(m, off));
    if ((tid & 63) == 0) red[tid >> 6] = m;
    __syncthreads();
    if (tid == 0)
        sjmax[b] = fmaxf(fmaxf(red[0], red[1]), fmaxf(red[2], red[3]));

    float4* out4 = (float4*)(FH + (long long)b * 4096);   // float2[2048]
    float4 w;
    w.x = __builtin_amdgcn_exp2f(v0.x); w.y = __builtin_amdgcn_exp2f(ALPHA * v0.x);
    w.z = __builtin_amdgcn_exp2f(v0.y); w.w = __builtin_amdgcn_exp2f(ALPHA * v0.y);
    out4[2*tid] = w;
    w.x = __builtin_amdgcn_exp2f(v0.z); w.y = __builtin_amdgcn_exp2f(ALPHA * v0.z);
    w.z = __builtin_amdgcn_exp2f(v0.w); w.w = __builtin_amdgcn_exp2f(ALPHA * v0.w);
    out4[2*tid + 1] = w;
    w.x = __builtin_amdgcn_exp2f(v1.x); w.y = __builtin_amdgcn_exp2f(ALPHA * v1.x);
    w.z = __builtin_amdgcn_exp2f(v1.y); w.w = __builtin_amdgcn_exp2f(ALPHA * v1.y);
    out4[512 + 2*tid] = w;
    w.x = __builtin_amdgcn_exp2f(v1.z); w.y = __builtin_amdgcn_exp2f(ALPHA * v1.z);
    w.z = __builtin_amdgcn_exp2f(v1.w); w.w = __builtin_amdgcn_exp2f(ALPHA * v1.w);
    out4[512 + 2*tid + 1] = w;
}

// ---------------------------------------------------------------------------
// Kernel B: fused masked-softmax attention. Fixed per-row max, factorized exp
// (no transcendentals in the hot loop), 2-deep adj prefetch, FH in LDS
// (broadcast reads). p = adj ? (Fj>TF ? Ei*Fj : Gi*Hj) : 0.
// ---------------------------------------------------------------------------
__global__ __launch_bounds__(256) void gat_attention(
    const int* __restrict__ adj, const unsigned short* __restrict__ WhT,
    const float* __restrict__ si2, const float* __restrict__ FH,
    const float* __restrict__ sjmax, float* __restrict__ out)
{
    __shared__ float2 fh_lds[2048];          // 16 KB
    __shared__ float l_lds[4][16];
    __shared__ float acc_lds[4][16][64];     // 16 KB

    const int tid  = threadIdx.x;
    const int lane = tid & 63;
    const int wave = tid >> 6;
    const int bid  = blockIdx.x;
    const int b    = bid >> 7;
    const int i0   = (bid & 127) << 4;

    const int arow = lane & 15;          // P-row / output o-col index
    const int g    = lane >> 4;          // k-group

    const int* aptr = adj + (((long long)b * 2048) + i0 + arow) * 2048
                          + wave * 512 + g * 8;
    const int jbase = wave * 512 + g * 8;
    const unsigned short* whb = WhT + (long long)b * 64 * 2048;

    // 2-deep adj prefetch (plain cached loads)
    i32x4 A0 = *(const i32x4*)(aptr);
    i32x4 A1 = *(const i32x4*)(aptr + 4);
    i32x4 B0 = *(const i32x4*)(aptr + 32);
    i32x4 B1 = *(const i32x4*)(aptr + 36);

    // stage FH tables (coalesced global -> LDS)
    {
        const float4* g4 = (const float4*)(FH + (long long)b * 4096);
        float4* l4 = (float4*)fh_lds;
        #pragma unroll
        for (int i = 0; i < 4; ++i) {
            int idx = tid + i * 256;     // 0..1023
            l4[idx] = g4[idx];
        }
    }

    const float mysi = si2[b * 2048 + i0 + arow];
    const float u    = mysi + sjmax[b];
    const float m2   = fmaxf(u, ALPHA * u);               // fixed row max
    const float Ei   = __builtin_amdgcn_exp2f(mysi - m2);
    const float Gi   = __builtin_amdgcn_exp2f(ALPHA * mysi - m2);
    const float TF   = __builtin_amdgcn_exp2f(-mysi);

    f32x4 accf[4];
    #pragma unroll
    for (int ob = 0; ob < 4; ++ob) accf[ob] = (f32x4){0.f, 0.f, 0.f, 0.f};
    f32x4 accl = (f32x4){0.f, 0.f, 0.f, 0.f};

    bf16x8 ones;
    #pragma unroll
    for (int k = 0; k < 8; ++k) ones[k] = (short)0x3F80;  // bf16 1.0

    __syncthreads();   // FH staged (also drains the adj prefetch: pipeline fill)

    auto process = [&](i32x4 C0, i32x4 C1, int jc) {
        const int jl = jbase + jc;
        const float4* fh4 = (const float4*)(fh_lds + jl);  // (F,H,F,H)
        const float4 q0 = fh4[0];
        const float4 q1 = fh4[1];
        const float4 q2 = fh4[2];
        const float4 q3 = fh4[3];
        float p[8];
        p[0] = C0[0] > 0 ? (q0.x > TF ? Ei*q0.x : Gi*q0.y) : 0.f;
        p[1] = C0[1] > 0 ? (q0.z > TF ? Ei*q0.z : Gi*q0.w) : 0.f;
        p[2] = C0[2] > 0 ? (q1.x > TF ? Ei*q1.x : Gi*q1.y) : 0.f;
        p[3] = C0[3] > 0 ? (q1.z > TF ? Ei*q1.z : Gi*q1.w) : 0.f;
        p[4] = C1[0] > 0 ? (q2.x > TF ? Ei*q2.x : Gi*q2.y) : 0.f;
        p[5] = C1[1] > 0 ? (q2.z > TF ? Ei*q2.z : Gi*q2.w) : 0.f;
        p[6] = C1[2] > 0 ? (q3.x > TF ? Ei*q3.x : Gi*q3.y) : 0.f;
        p[7] = C1[3] > 0 ? (q3.z > TF ? Ei*q3.z : Gi*q3.w) : 0.f;

        i32x4 pk;
        pk[0] = cvt_pk_bf16(p[0], p[1]);
        pk[1] = cvt_pk_bf16(p[2], p[3]);
        pk[2] = cvt_pk_bf16(p[4], p[5]);
        pk[3] = cvt_pk_bf16(p[6], p[7]);
        const bf16x8 pa = __builtin_bit_cast(bf16x8, pk);

        accl = __builtin_amdgcn_mfma_f32_16x16x32_bf16(pa, ones, accl, 0, 0, 0);
        #pragma unroll
        for (int ob = 0; ob < 4; ++ob) {
            const bf16x8 bfr =
                *(const bf16x8*)(whb + (long long)(ob*16 + arow)*2048 + jl);
            accf[ob] = __builtin_amdgcn_mfma_f32_16x16x32_bf16(pa, bfr, accf[ob], 0, 0, 0);
        }
    };

    for (int jc = 0; jc < 512; jc += 32) {
        const int pf = (jc < 448) ? jc + 64 : 0;   // uniform; tail re-reads chunk 0 (cache hit)
        const i32x4 N0 = *(const i32x4*)(aptr + pf);
        const i32x4 N1 = *(const i32x4*)(aptr + pf + 4);
        process(A0, A1, jc);
        A0 = B0; A1 = B1; B0 = N0; B1 = N1;
    }

    // ---- combine the 4 j-quarter partials (shared m => plain sums) ----
    if (arow == 0) {
        #pragma unroll
        for (int r = 0; r < 4; ++r) l_lds[wave][g*4 + r] = accl[r];
    }
    #pragma unroll
    for (int r = 0; r < 4; ++r) {
        #pragma unroll
        for (int ob = 0; ob < 4; ++ob)
            acc_lds[wave][g*4 + r][ob*16 + arow] = accf[ob][r];
    }
    __syncthreads();

    const int oo = tid & 63;
    for (int rr = tid >> 6; rr < 16; rr += 4) {
        const float L = l_lds[0][rr] + l_lds[1][rr] + l_lds[2][rr] + l_lds[3][rr];
        const float s = acc_lds[0][rr][oo] + acc_lds[1][rr][oo]
                      + acc_lds[2][rr][oo] + acc_lds[3][rr][oo];
        out[(((long long)b*2048) + i0 + rr)*64 + oo] = s / L;
    }
}

// ---------------------------------------------------------------------------
extern "C" void kernel_launch(void* const* d_in, const int* in_sizes, int n_in,
                              void* d_out, int out_size, void* d_ws, size_t ws_size,
                              hipStream_t stream) {
    const float* h   = (const float*)d_in[0];
    const int*   adj = (const int*)d_in[1];
    const float* W   = (const float*)d_in[2];
    const float* a   = (const float*)d_in[3];
    float* out = (float*)d_out;

    unsigned short* WhT = (unsigned short*)d_ws;                    // 2 MB
    float* si2   = (float*)((char*)d_ws + (size_t)8*64*2048*2);
    float* sj2   = si2 + 8*2048;
    float* sjmax = sj2 + 8*2048;
    float* FH    = sjmax + 8;                                       // float2[8][2048]

    gat_precompute<<<512, 256, 0, stream>>>(h, W, a, WhT, si2, sj2);
    gat_tables<<<8, 256, 0, stream>>>(sj2, sjmax, FH);
    gat_attention<<<1024, 256, 0, stream>>>(adj, WhT, si2, FH, sjmax, out);
}

// Round 5
// 48.242 us; speedup vs baseline: 1.8477x; 1.3800x over previous
//
#include <hip/hip_runtime.h>
#include <hip/hip_bf16.h>

#define ALPHA 0.2f
#define LOG2E 1.4426950408889634f

typedef __attribute__((ext_vector_type(8))) short bf16x8;
typedef __attribute__((ext_vector_type(4))) float f32x4;
typedef __attribute__((ext_vector_type(4))) int i32x4;

__device__ __forceinline__ int cvt_pk_bf16(float lo, float hi) {
    int r;
    asm("v_cvt_pk_bf16_f32 %0, %1, %2" : "=v"(r) : "v"(lo), "v"(hi));
    return r;
}

// async global->LDS, 16B per lane; LDS dest = wave-uniform base + lane*16
__device__ __forceinline__ void stage16(const void* g, void* l) {
    __builtin_amdgcn_global_load_lds(
        (const __attribute__((address_space(1))) void*)g,
        (__attribute__((address_space(3))) void*)l, 16, 0, 0);
}

// ---------------------------------------------------------------------------
// Kernel A (round-3 verbatim, verified): Wh = h @ W (fp32), si2/sj2 scaled by
// log2e, WhT = bf16(Wh)^T o-major [b][64][2048]. 512 blocks x 256 threads.
// ---------------------------------------------------------------------------
__global__ __launch_bounds__(256) void gat_precompute(
    const float* __restrict__ h, const float* __restrict__ W,
    const float* __restrict__ a, unsigned short* __restrict__ WhT,
    float* __restrict__ si2, float* __restrict__ sj2)
{
    __shared__ float h_lds[32][128];
    __shared__ float wh_lds[32][65];   // +1 pad
    const int tid  = threadIdx.x;
    const int lane = tid & 63;
    const int wave = tid >> 6;
    const long long row0 = (long long)blockIdx.x * 32;

    {
        const float4* s4 = (const float4*)(h + row0 * 128);
        #pragma unroll
        for (int i = 0; i < 4; ++i) {
            int idx = tid + i * 256;
            float4 v = s4[idx];
            *(float4*)&h_lds[idx >> 5][(idx & 31) * 4] = v;
        }
    }
    __syncthreads();

    const float a1 = a[lane];
    const float a2 = a[64 + lane];
    float acc[8];
    #pragma unroll
    for (int r = 0; r < 8; ++r) acc[r] = 0.0f;

    for (int f = 0; f < 128; f += 4) {
        const float w0 = W[(f+0)*64 + lane];
        const float w1 = W[(f+1)*64 + lane];
        const float w2 = W[(f+2)*64 + lane];
        const float w3 = W[(f+3)*64 + lane];
        #pragma unroll
        for (int r = 0; r < 8; ++r) {
            const float4 hv = *(const float4*)&h_lds[wave*8 + r][f];
            acc[r] = fmaf(hv.x, w0, acc[r]);
            acc[r] = fmaf(hv.y, w1, acc[r]);
            acc[r] = fmaf(hv.z, w2, acc[r]);
            acc[r] = fmaf(hv.w, w3, acc[r]);
        }
    }

    #pragma unroll
    for (int r = 0; r < 8; ++r) {
        const int rr = wave*8 + r;
        wh_lds[rr][lane] = acc[r];
        float s1 = acc[r] * a1;
        float s2 = acc[r] * a2;
        #pragma unroll
        for (int off = 32; off > 0; off >>= 1) {
            s1 += __shfl_xor(s1, off);
            s2 += __shfl_xor(s2, off);
        }
        if (lane == 0) {
            si2[row0 + rr] = s1 * LOG2E;
            sj2[row0 + rr] = s2 * LOG2E;
        }
    }
    __syncthreads();

    // transposed bf16 write: 64 o-rows x 32 n-cols
    const long long b  = row0 >> 11;
    const int n0 = (int)(row0 & 2047);
    const int o  = tid >> 2;
    const int c0 = (tid & 3) * 8;
    i32x4 pk;
    #pragma unroll
    for (int k = 0; k < 4; ++k)
        pk[k] = cvt_pk_bf16(wh_lds[c0 + 2*k][o], wh_lds[c0 + 2*k + 1][o]);
    *(i32x4*)(WhT + (b*64 + o)*2048 + n0 + c0) = pk;
}

// ---------------------------------------------------------------------------
// Kernel B: fused masked-softmax attention, fully LDS-staged via
// global_load_lds. Block = (b, 32 i-rows); 4 waves: (wave&1)=row-group,
// (wave>>1)=j-half; 16 double-buffered steps of 64 j per half.
// adj tile [32 rows][32 units x 16B], unit swizzle u = pu ^ (row&15).
// WhT tile per half: [64 o][8 slots x 16B] o-major, slot swizzle pu ^ (o&7);
// B-fragment = one aligned ds_read_b128 (same data layout rounds 1-3 used).
// p = exp2(max(Ci+sj, 0.2*sj+Di)) * (adj>0), fixed row max (lrelu monotone).
// ---------------------------------------------------------------------------
__global__ __launch_bounds__(256) void gat_attention(
    const int* __restrict__ adj, const unsigned short* __restrict__ WhT,
    const float* __restrict__ si2, const float* __restrict__ sj2,
    float* __restrict__ out)
{
    __shared__ char ldsbuf[65536];   // [s][adj 16K | wh 16K] x2
    const int tid  = threadIdx.x;
    const int lane = tid & 63;
    const int wave = tid >> 6;
    const int bid  = blockIdx.x;
    const int b    = bid >> 6;
    const int i0   = (bid & 63) << 5;   // *32
    const int arow = lane & 15;
    const int g    = lane >> 4;
    const int half = wave >> 1;
    const int rgrp = wave & 1;
    const long long bN = (long long)b * 2048;

    // ---- adj staging sources (per-lane; uniform advance per step) ----
    const int* asrc[4];
    #pragma unroll
    for (int rd = 0; rd < 4; ++rd) {
        int U = (wave*4 + rd)*64 + lane;
        int r = U >> 5, pu = U & 31;
        int u = pu ^ (r & 15);                         // logical 16B unit
        int col = (u < 16) ? u*4 : (1024 + (u-16)*4);  // ints, before j0
        asrc[rd] = adj + (bN + i0 + r)*2048 + col;
    }
    // ---- WhT staging sources: unit U = wave*256+rd*64+lane of 1024 ----
    // half = U>>9; within half: o = (U&511)>>3, slot pu = U&7;
    // source slot = pu ^ (o&7)  (inverse swizzle on SOURCE, linear dest)
    const unsigned short* wsrc[4];
    #pragma unroll
    for (int rd = 0; rd < 4; ++rd) {
        int U  = wave*256 + rd*64 + lane;
        int hf = U >> 9;
        int o  = (U & 511) >> 3;
        int pu = U & 7;
        wsrc[rd] = WhT + ((long long)b*64 + o)*2048 + hf*1024
                       + ((pu ^ (o & 7)) * 8);
    }

    // ---- per-batch sjmax (block-redundant, once) ----
    const float* sjb = sj2 + bN;
    float mx = -INFINITY;
    #pragma unroll 4
    for (int i = 0; i < 32; ++i) mx = fmaxf(mx, sjb[lane + i*64]);
    #pragma unroll
    for (int off = 32; off > 0; off >>= 1) mx = fmaxf(mx, __shfl_xor(mx, off));

    const float si_r = si2[bN + i0 + rgrp*16 + arow];
    const float u0f  = si_r + mx;
    const float m2   = fmaxf(u0f, ALPHA * u0f);     // fixed row max (log2 dom)
    const float Ci   = si_r - m2;
    const float Di   = ALPHA * si_r - m2;
    const int   rr   = rgrp*16 + arow;              // adj tile row

    f32x4 accf[4];
    #pragma unroll
    for (int ob = 0; ob < 4; ++ob) accf[ob] = (f32x4){0.f,0.f,0.f,0.f};
    f32x4 accl = (f32x4){0.f,0.f,0.f,0.f};
    bf16x8 ones;
    #pragma unroll
    for (int k = 0; k < 8; ++k) ones[k] = (short)0x3F80;

    #define STAGE(S, STEP) { \
        const int ja = (STEP) * 64; \
        char* ab_ = ldsbuf + (S)*32768; \
        stage16(asrc[0] + ja, ab_ + (wave*4+0)*1024); \
        stage16(asrc[1] + ja, ab_ + (wave*4+1)*1024); \
        stage16(asrc[2] + ja, ab_ + (wave*4+2)*1024); \
        stage16(asrc[3] + ja, ab_ + (wave*4+3)*1024); \
        char* wb_ = ldsbuf + (S)*32768 + 16384 + wave*4096; \
        stage16(wsrc[0] + ja, wb_ + 0*1024); \
        stage16(wsrc[1] + ja, wb_ + 1*1024); \
        stage16(wsrc[2] + ja, wb_ + 2*1024); \
        stage16(wsrc[3] + ja, wb_ + 3*1024); \
    }

    #define KKBODY(KK) { \
        const char* wb = ab + 16384 + half*8192; \
        const int ws = ((KK)*4 + g) ^ (arow & 7); \
        const bf16x8 bf0 = *(const bf16x8*)(wb + (( 0 + arow)*8 + ws)*16); \
        const bf16x8 bf1 = *(const bf16x8*)(wb + ((16 + arow)*8 + ws)*16); \
        const bf16x8 bf2 = *(const bf16x8*)(wb + ((32 + arow)*8 + ws)*16); \
        const bf16x8 bf3 = *(const bf16x8*)(wb + ((48 + arow)*8 + ws)*16); \
        const int u0a = half*16 + (KK)*8 + g*2; \
        const i32x4 A0 = *(const i32x4*)(ab + rr*512 + ((u0a    ) ^ arow)*16); \
        const i32x4 A1 = *(const i32x4*)(ab + rr*512 + ((u0a + 1) ^ arow)*16); \
        const float* sjp = sjb + half*1024 + j0 + (KK)*32 + g*8; \
        const f32x4 S0 = *(const f32x4*)(sjp); \
        const f32x4 S1 = *(const f32x4*)(sjp + 4); \
        float p[8]; \
        _Pragma("unroll") \
        for (int e = 0; e < 4; ++e) { \
            float pe = __builtin_amdgcn_exp2f( \
                fmaxf(Ci + S0[e], fmaf(ALPHA, S0[e], Di))); \
            p[e] = (A0[e] > 0) ? pe : 0.0f; \
        } \
        _Pragma("unroll") \
        for (int e = 0; e < 4; ++e) { \
            float pe = __builtin_amdgcn_exp2f( \
                fmaxf(Ci + S1[e], fmaf(ALPHA, S1[e], Di))); \
            p[4+e] = (A1[e] > 0) ? pe : 0.0f; \
        } \
        i32x4 pk_; \
        pk_[0] = cvt_pk_bf16(p[0], p[1]); \
        pk_[1] = cvt_pk_bf16(p[2], p[3]); \
        pk_[2] = cvt_pk_bf16(p[4], p[5]); \
        pk_[3] = cvt_pk_bf16(p[6], p[7]); \
        const bf16x8 pa = __builtin_bit_cast(bf16x8, pk_); \
        accl    = __builtin_amdgcn_mfma_f32_16x16x32_bf16(pa, ones, accl, 0, 0, 0); \
        accf[0] = __builtin_amdgcn_mfma_f32_16x16x32_bf16(pa, bf0, accf[0], 0, 0, 0); \
        accf[1] = __builtin_amdgcn_mfma_f32_16x16x32_bf16(pa, bf1, accf[1], 0, 0, 0); \
        accf[2] = __builtin_amdgcn_mfma_f32_16x16x32_bf16(pa, bf2, accf[2], 0, 0, 0); \
        accf[3] = __builtin_amdgcn_mfma_f32_16x16x32_bf16(pa, bf3, accf[3], 0, 0, 0); \
    }

    STAGE(0, 0);
    __syncthreads();

    int s = 0;
    for (int st = 0; st < 16; ++st) {
        if (st < 15) STAGE(s^1, st+1);
        const char* ab = ldsbuf + s*32768;
        const int j0 = st * 64;
        KKBODY(0);
        KKBODY(1);
        __syncthreads();
        s ^= 1;
    }

    // ---- epilogue: combine j-halves, divide by row sum, store ----
    float* accb = (float*)ldsbuf;            // [4][16][64]
    float* lb   = (float*)(ldsbuf + 16384);  // [4][16]
    #pragma unroll
    for (int ob = 0; ob < 4; ++ob)
        #pragma unroll
        for (int rg2 = 0; rg2 < 4; ++rg2)
            accb[(wave*16 + g*4 + rg2)*64 + ob*16 + arow] = accf[ob][rg2];
    if (arow == 0) {
        #pragma unroll
        for (int rg2 = 0; rg2 < 4; ++rg2)
            lb[wave*16 + g*4 + rg2] = accl[rg2];
    }
    __syncthreads();

    const int r  = tid >> 3;            // 0..31
    const int o0 = (tid & 7) * 8;
    const int rg = r >> 4, rl = r & 15;
    const float L   = lb[rg*16 + rl] + lb[(rg+2)*16 + rl];
    const float inv = 1.0f / L;
    float ov[8];
    #pragma unroll
    for (int k = 0; k < 8; ++k)
        ov[k] = (accb[(rg*16 + rl)*64 + o0 + k]
               + accb[((rg+2)*16 + rl)*64 + o0 + k]) * inv;
    float* op = out + (bN + i0 + r)*64 + o0;
    *(float4*)op       = (float4){ov[0], ov[1], ov[2], ov[3]};
    *(float4*)(op + 4) = (float4){ov[4], ov[5], ov[6], ov[7]};
}

// ---------------------------------------------------------------------------
extern "C" void kernel_launch(void* const* d_in, const int* in_sizes, int n_in,
                              void* d_out, int out_size, void* d_ws, size_t ws_size,
                              hipStream_t stream) {
    const float* h   = (const float*)d_in[0];
    const int*   adj = (const int*)d_in[1];
    const float* W   = (const float*)d_in[2];
    const float* a   = (const float*)d_in[3];
    float* out = (float*)d_out;

    unsigned short* WhT = (unsigned short*)d_ws;                // 2 MB bf16 [b][64][2048]
    float* si2 = (float*)((char*)d_ws + (size_t)16384*64*2);
    float* sj2 = si2 + 16384;

    gat_precompute<<<512, 256, 0, stream>>>(h, W, a, WhT, si2, sj2);
    gat_attention<<<512, 256, 0, stream>>>(adj, WhT, si2, sj2, out);
}